// Round 1
// baseline (328.660 us; speedup 1.0000x reference)
//
#include <hip/hip_runtime.h>

#define D 128
#define RPB 32          // rows per bucket
#define SHIFT 5         // log2(RPB)
#define PB 256          // partition blocks
#define CAP 1536        // max edges per bucket chunk (avg 512)

typedef __attribute__((ext_vector_type(8))) short short8;
typedef __attribute__((ext_vector_type(4))) float f32x4;
typedef __attribute__((ext_vector_type(2))) float f32x2;

// ---- bf16 pack helpers (round-to-nearest-even)
__device__ inline unsigned bfr(float f) {
  unsigned u = __float_as_uint(f);
  return (u + 0x7fffu + ((u >> 16) & 1u)) >> 16;
}
__device__ inline unsigned pack2(float lo, float hi) {
  return bfr(lo) | (bfr(hi) << 16);
}

// ---------------- hist: dual LDS histograms + GLOBAL per-row in-degree atomics.
// role B (64 blocks): W1 fp32 -> bf16 transposed Wtg
__global__ __launch_bounds__(256) void k_hist(const int* __restrict__ dst,
                                              const int* __restrict__ src,
                                              int* __restrict__ phT,
                                              const float* __restrict__ W,
                                              unsigned short* __restrict__ Wtg,
                                              int* __restrict__ deg,
                                              int E, int NBKT, int ECH, int K2) {
  __shared__ int hist[6400];
  int b = blockIdx.x, t = threadIdx.x;
  if (b >= PB) {
    int i = (b - PB) * 256 + t;
    if (i < 128 * 128) {
      int k = i >> 7, n = i & 127;
      Wtg[n * 128 + k] = (unsigned short)bfr(W[k * 128 + n]);
    }
    return;
  }
  int* histD = hist;
  int* histS = hist + NBKT;
  for (int k = t; k < K2; k += 256) hist[k] = 0;
  __syncthreads();
  int st = b * ECH, en = min(E, st + ECH);
  for (int i = st + t; i < en; i += 256) {
    int d = dst[i], s = src[i];
    atomicAdd(&histD[d >> SHIFT], 1);
    atomicAdd(&histS[s >> SHIFT], 1);
    atomicAdd(&deg[d], 1);  // fire-and-forget, no return
  }
  __syncthreads();
  for (int k = t; k < K2; k += 256) phT[(size_t)b * K2 + k] = hist[k];
}

// ---------------- tots: per-bucket totals over blocks (role A) + dinv = rsqrt(deg+1) (role B)
__global__ __launch_bounds__(256) void k_tots(const int* __restrict__ phT,
                                              int* __restrict__ tot,
                                              const int* __restrict__ deg,
                                              float* __restrict__ dinv,
                                              int K2, int N, int TB) {
  int b = blockIdx.x, t = threadIdx.x;
  if (b < TB) {
    int k = b * 256 + t;
    if (k < K2) {
      int s = 0;
      for (int bb = 0; bb < PB; ++bb) s += phT[(size_t)bb * K2 + k];
      tot[k] = s;
    }
  } else {
    int r = (b - TB) * 256 + t;
    if (r < N) dinv[r] = rsqrtf((float)deg[r] + 1.0f);  // +1 self-loop
  }
}

// ---------------- scan3: redundant in-LDS exclusive scan of tot (K2 entries),
// then per-bucket column rewrite of phT to running prefixes
__global__ __launch_bounds__(256) void k_scan3(int* __restrict__ phT,
                                               const int* __restrict__ tot, int K2) {
  __shared__ int ltot[6400];
  __shared__ int sc[256];
  int t = threadIdx.x;
  for (int i = t; i < K2; i += 256) ltot[i] = tot[i];
  __syncthreads();
  int C = (K2 + 255) / 256;
  int c0 = t * C;
  int s = 0;
  for (int j = 0; j < C; ++j) {
    int idx = c0 + j;
    if (idx < K2) s += ltot[idx];
  }
  sc[t] = s;
  __syncthreads();
  for (int off = 1; off < 256; off <<= 1) {
    int x = (t >= off) ? sc[t - off] : 0;
    __syncthreads();
    sc[t] += x;
    __syncthreads();
  }
  int run = sc[t] - s;
  for (int j = 0; j < C; ++j) {
    int idx = c0 + j;
    if (idx < K2) {
      int v = ltot[idx];
      ltot[idx] = run;
      run += v;
    }
  }
  __syncthreads();

  int k = blockIdx.x * 256 + t;
  if (k < K2) {
    int r = ltot[k];
    for (int b = 0; b < PB; ++b) {
      size_t idx = (size_t)b * K2 + k;
      int v = phT[idx];
      phT[idx] = r;
      r += v;
    }
  }
}

// ---------------- FUSED: dual pscat (role A, PB blocks, XCD-remapped) || MFMA gemm
// GEMM epilogue now PRESCALES by dinv[row]: hu8[r] = fp8(dinv[r] * (x@W1)[r])
__global__ __launch_bounds__(256) void k_scat_gemm(
    const int* __restrict__ src, const int* __restrict__ dst,
    const int* __restrict__ phT, int* __restrict__ eb,
    const float* __restrict__ x, const unsigned short* __restrict__ Wtg,
    const float* __restrict__ dinv,
    unsigned short* __restrict__ hu8, int M, int E, int NBKT, int ECH, int K2) {
  __shared__ int shm[6400];  // 25.6 KB: cursors or gemm x-tile
  int p = blockIdx.x, t = threadIdx.x;

  if (p < PB) {
    int b = ((p & 7) << 5) | (p >> 3);
    int* curD = shm;
    int* curS = shm + NBKT;
    for (int k = t; k < K2; k += 256) shm[k] = phT[(size_t)b * K2 + k];
    __syncthreads();
    int st = b * ECH, en = min(E, st + ECH);
    for (int i = st + t * 4; i < en; i += 1024) {
      if (i + 3 < en) {
        int4 s4 = *(const int4*)(src + i);
        int4 d4 = *(const int4*)(dst + i);
        int p0 = atomicAdd(&curD[d4.x >> SHIFT], 1);
        int p1 = atomicAdd(&curD[d4.y >> SHIFT], 1);
        int p2 = atomicAdd(&curD[d4.z >> SHIFT], 1);
        int p3 = atomicAdd(&curD[d4.w >> SHIFT], 1);
        eb[p0] = s4.x | ((d4.x & (RPB - 1)) << 26);
        eb[p1] = s4.y | ((d4.y & (RPB - 1)) << 26);
        eb[p2] = s4.z | ((d4.z & (RPB - 1)) << 26);
        eb[p3] = s4.w | ((d4.w & (RPB - 1)) << 26);
        int q0 = atomicAdd(&curS[s4.x >> SHIFT], 1);
        int q1 = atomicAdd(&curS[s4.y >> SHIFT], 1);
        int q2 = atomicAdd(&curS[s4.z >> SHIFT], 1);
        int q3 = atomicAdd(&curS[s4.w >> SHIFT], 1);
        eb[q0] = d4.x | ((s4.x & (RPB - 1)) << 26);
        eb[q1] = d4.y | ((s4.y & (RPB - 1)) << 26);
        eb[q2] = d4.z | ((s4.z & (RPB - 1)) << 26);
        eb[q3] = d4.w | ((s4.w & (RPB - 1)) << 26);
      } else {
        for (int j = i; j < en; ++j) {
          int d = dst[j], s = src[j];
          int pos = atomicAdd(&curD[d >> SHIFT], 1);
          eb[pos] = s | ((d & (RPB - 1)) << 26);
          int qos = atomicAdd(&curS[s >> SHIFT], 1);
          eb[qos] = d | ((s & (RPB - 1)) << 26);
        }
      }
    }
    return;
  }

  // ---- MFMA gemm role: h = dinv * (x@W1), fp8 e4m3 packed
  int row0 = (p - PB) * 64;
  if (row0 >= M) return;
  unsigned short* xs = (unsigned short*)shm;  // [64][136]

  for (int i = t; i < 2048; i += 256) {
    int r = i >> 5;
    int rg = row0 + r;
    int rc = rg < M ? rg : M - 1;
    float4 v = ((const float4*)x)[(size_t)rc * 32 + (i & 31)];
    *(uint2*)&xs[r * 136 + (i & 31) * 4] = make_uint2(pack2(v.x, v.y), pack2(v.z, v.w));
  }
  __syncthreads();

  int lane = t & 63;
  int wid = t >> 6;
  int l15 = lane & 15;
  int quad = lane >> 4;
  int mloc = wid * 16 + l15;

  f32x4 acc[8];
  #pragma unroll
  for (int ct = 0; ct < 8; ++ct) acc[ct] = (f32x4){0.f, 0.f, 0.f, 0.f};

  #pragma unroll
  for (int k0 = 0; k0 < 128; k0 += 32) {
    short8 af = *(const short8*)&xs[mloc * 136 + k0 + quad * 8];
    #pragma unroll
    for (int ct = 0; ct < 8; ++ct) {
      short8 bf = *(const short8*)(Wtg + (ct * 16 + l15) * 128 + k0 + quad * 8);
      acc[ct] = __builtin_amdgcn_mfma_f32_16x16x32_bf16(af, bf, acc[ct], 0, 0, 0);
    }
  }

  int rowbase = row0 + wid * 16 + quad * 4;
  #pragma unroll
  for (int r = 0; r < 4; ++r) {
    int row = rowbase + r;
    float di = dinv[row < M ? row : M - 1];
    #pragma unroll
    for (int ct = 0; ct < 8; ++ct) {
      float v = acc[ct][r] * di;
      float vp = __shfl_xor(v, 1, 64);
      if (!(lane & 1) && row < M) {
        int pk = __builtin_amdgcn_cvt_pk_fp8_f32(v, vp, 0, false);
        hu8[(size_t)row * 64 + ct * 8 + (l15 >> 1)] = (unsigned short)(pk & 0xffff);
      }
    }
  }
}

// ---------------- ssum (src partition, standalone so k_bagg can consume it):
// ssum[r] = sum dinv[dst] over out-edges of r
__global__ __launch_bounds__(256) void k_ssum(const int* __restrict__ eb,
                                              const int* __restrict__ phT,
                                              const float* __restrict__ dinv,
                                              float* __restrict__ ssum,
                                              int N, int E, int NBKT, int K2) {
  __shared__ float sums[RPB];
  int sb = blockIdx.x, t = threadIdx.x;
  if (t < RPB) sums[t] = 0.f;
  __syncthreads();
  int lo = phT[NBKT + sb];
  int hi = (NBKT + sb + 1 < K2) ? phT[NBKT + sb + 1] : 2 * E;
  for (int i = lo + t; i < hi; i += 256) {
    int v = eb[i];
    atomicAdd(&sums[(unsigned)v >> 26], dinv[v & 0x3FFFFFF]);
  }
  __syncthreads();
  if (t < RPB) {
    int r = sb * RPB + t;
    if (r < N) ssum[r] = sums[t];
  }
}

// ---------------- bucketed aggregate + FUSED weighted reduce:
// vpart[bkt][f] = sum_{r in bkt} w[r]*a1[r][f],  w[r]=dinv[r]*(ssum[r]+dinv[r])
// hu8 holds dinv-prescaled h, so the inner loop needs NO dinv gather; per-row
// edge lists are processed in padded 8-wide batches (no serial remainder).
__global__ __launch_bounds__(256) void k_bagg(
    const unsigned short* __restrict__ hu8, const int* __restrict__ eb,
    const int* __restrict__ phT, const float* __restrict__ dinv,
    const float* __restrict__ ssum, const float* __restrict__ b1,
    float* __restrict__ vpart, int N) {
  __shared__ int raw[CAP];
  __shared__ int srt[CAP];
  __shared__ int rh[RPB + 1];
  __shared__ int rcur[RPB];
  int bkt = blockIdx.x, t = threadIdx.x;
  int lane = t & 63, wid = t >> 6;
  int lo = phT[bkt];
  int hi = phT[bkt + 1];

  float ax[8], ay[8];
  #pragma unroll
  for (int k = 0; k < 8; ++k) { ax[k] = 0.f; ay[k] = 0.f; }

  for (int clo = lo; clo < hi; clo += CAP) {
    int cnt = min(CAP, hi - clo);
    if (t <= RPB) rh[t] = 0;
    __syncthreads();
    for (int i = t; i < cnt; i += 256) {
      int v = eb[clo + i];
      raw[i] = v;
      atomicAdd(&rh[((unsigned)v >> 26) + 1], 1);
    }
    __syncthreads();
    if (t < 32) {
      int x = rh[t + 1];
      #pragma unroll
      for (int o = 1; o < 32; o <<= 1) {
        int y = __shfl_up(x, o, 64);
        if (t >= o) x += y;
      }
      rh[t + 1] = x;
    }
    __syncthreads();
    if (t < RPB) rcur[t] = rh[t];
    __syncthreads();
    for (int i = t; i < cnt; i += 256) {
      int v = raw[i];
      int r = (unsigned)v >> 26;
      int pos = atomicAdd(&rcur[r], 1);
      srt[pos] = v & 0x3FFFFFF;
    }
    __syncthreads();

    #pragma unroll
    for (int k = 0; k < 8; ++k) {
      int rl = wid + k * 4;
      int beg = rh[rl], end = rh[rl + 1];
      for (int j = beg; j < end; j += 8) {
        #pragma unroll
        for (int d = 0; d < 8; ++d) {
          int jd = j + d;
          int s = srt[jd < end ? jd : end - 1];
          unsigned v = hu8[(s << 6) + lane];
          float m = (jd < end) ? 1.f : 0.f;
          f32x2 f = __builtin_amdgcn_cvt_pk_f32_fp8((int)v, false);
          ax[k] = fmaf(m, f.x, ax[k]);
          ay[k] = fmaf(m, f.y, ay[k]);
        }
      }
    }
    __syncthreads();
  }

  // epilogue: a1 = relu(di*(acc + hs_self) + b1); accumulate w*a1 into partial
  float2 bb = *(const float2*)(b1 + lane * 2);
  float vx = 0.f, vy = 0.f;
  #pragma unroll
  for (int k = 0; k < 8; ++k) {
    int r = bkt * RPB + wid + k * 4;
    if (r < N) {
      float di = dinv[r];
      unsigned gr = hu8[(r << 6) + lane];
      f32x2 fg = __builtin_amdgcn_cvt_pk_f32_fp8((int)gr, false);
      float hx = fmaxf(fmaf(di, ax[k] + fg.x, bb.x), 0.f);
      float hy = fmaxf(fmaf(di, ay[k] + fg.y, bb.y), 0.f);
      float w = di * (ssum[r] + di);
      vx = fmaf(w, hx, vx);
      vy = fmaf(w, hy, vy);
    }
  }
  float2* red = (float2*)raw;  // reuse LDS (all srt/raw reads done)
  red[t] = make_float2(vx, vy);
  __syncthreads();
  if (t < 64) {
    float2 a = red[t], b = red[t + 64], c = red[t + 128], d2 = red[t + 192];
    vpart[(size_t)bkt * D + t * 2]     = (a.x + b.x) + (c.x + d2.x);
    vpart[(size_t)bkt * D + t * 2 + 1] = (a.y + b.y) + (c.y + d2.y);
  }
}

// ---------------- vred2: reduce NBKT per-bucket partials -> 64 partials
__global__ __launch_bounds__(128) void k_vred2(const float* __restrict__ vpart,
                                               float* __restrict__ vpart2, int NBKT) {
  int t = threadIdx.x;
  float s = 0.f;
  for (int i = blockIdx.x; i < NBKT; i += 64) s += vpart[(size_t)i * D + t];
  vpart2[(size_t)blockIdx.x * D + t] = s;
}

// ---------------- final: v = sum partials; out = (1/N)*v@W2 + b2
__global__ __launch_bounds__(1024) void k_final(const float* __restrict__ vpart,
                                                int npart,
                                                const float* __restrict__ W2,
                                                const float* __restrict__ b2,
                                                float* __restrict__ out, float invN) {
  __shared__ float seg[8][128];
  __shared__ float vs[128];
  int t = threadIdx.x;
  int c = t & 127, sg = t >> 7;
  float s = 0.f;
  for (int b = sg; b < npart; b += 8) s += vpart[(size_t)b * D + c];
  seg[sg][c] = s;
  __syncthreads();
  if (t < 128) {
    float tot = 0.f;
    #pragma unroll
    for (int k = 0; k < 8; ++k) tot += seg[k][c];
    vs[c] = tot;
  }
  __syncthreads();
  if (t < 128) {
    float o = 0.f;
    for (int k = 0; k < 128; ++k) o = fmaf(vs[k], W2[k * D + c], o);
    out[c] = fmaf(o, invN, b2[c]);
  }
}

extern "C" void kernel_launch(void* const* d_in, const int* in_sizes, int n_in,
                              void* d_out, int out_size, void* d_ws, size_t ws_size,
                              hipStream_t stream) {
  const float* x  = (const float*)d_in[0];
  const int*   ei = (const int*)d_in[1];
  const float* W1 = (const float*)d_in[2];
  const float* b1 = (const float*)d_in[3];
  const float* W2 = (const float*)d_in[4];
  const float* b2 = (const float*)d_in[5];
  float* out = (float*)d_out;

  int N = in_sizes[0] / D;
  int E = in_sizes[1] / 2;
  const int* src = ei;
  const int* dst = ei + E;

  const int NBKT = (N + RPB - 1) / RPB;                    // 3125
  const int K2   = 2 * NBKT;                               // 6250 (both tables)
  const int ECH  = (((E + PB - 1) / PB) + 3) & ~3;         // 6252 (x4 aligned)
  const int TB   = (K2 + 255) / 256;                       // 25
  const int NDB  = (N + 255) / 256;                        // 391
  const int NGEMM = (N + 63) / 64;                         // 1563

  char* p = (char*)d_ws;
  float* ssum  = (float*)p;      p += (size_t)N * 4;
  float* dinv  = (float*)p;      p += (size_t)N * 4;
  int*   deg   = (int*)p;        p += (size_t)N * 4;
  int*   tot   = (int*)p;        p += 8192 * 4;
  int*   phT   = (int*)p;        p += (size_t)PB * K2 * 4;
  int*   eb    = (int*)p;        p += (size_t)(2 * E) * 4;
  p = (char*)(((uintptr_t)p + 255) & ~(uintptr_t)255);
  unsigned short* Wtg = (unsigned short*)p;  p += 128 * 128 * 2;
  p = (char*)(((uintptr_t)p + 255) & ~(uintptr_t)255);
  unsigned short* hu8 = (unsigned short*)p;  p += (size_t)N * 64 * 2;
  p = (char*)(((uintptr_t)p + 255) & ~(uintptr_t)255);
  float* vpart  = (float*)p;     p += (size_t)NBKT * D * 4;
  float* vpart2 = (float*)p;

  hipMemsetAsync(deg, 0, (size_t)N * 4, stream);

  k_hist<<<PB + 64, 256, 0, stream>>>(dst, src, phT, W1, Wtg, deg, E, NBKT, ECH, K2);

  k_tots<<<TB + NDB, 256, 0, stream>>>(phT, tot, deg, dinv, K2, N, TB);

  k_scan3<<<TB, 256, 0, stream>>>(phT, tot, K2);

  k_scat_gemm<<<PB + NGEMM, 256, 0, stream>>>(src, dst, phT, eb, x, Wtg, dinv, hu8,
                                              N, E, NBKT, ECH, K2);

  k_ssum<<<NBKT, 256, 0, stream>>>(eb, phT, dinv, ssum, N, E, NBKT, K2);

  k_bagg<<<NBKT, 256, 0, stream>>>(hu8, eb, phT, dinv, ssum, b1, vpart, N);

  k_vred2<<<64, 128, 0, stream>>>(vpart, vpart2, NBKT);

  k_final<<<1, 1024, 0, stream>>>(vpart2, 64, W2, b2, out, 1.0f / N);
}

// Round 2
// 283.330 us; speedup vs baseline: 1.1600x; 1.1600x over previous
//
#include <hip/hip_runtime.h>

#define D 128
#define RPB 32          // rows per bucket
#define SHIFT 5         // log2(RPB)
#define PB 256          // partition blocks
#define CAP 1536        // max edges per bucket chunk (avg 512)

typedef __attribute__((ext_vector_type(8))) short short8;
typedef __attribute__((ext_vector_type(4))) float f32x4;
typedef __attribute__((ext_vector_type(2))) float f32x2;

// ---- bf16 pack helpers (round-to-nearest-even)
__device__ inline unsigned bfr(float f) {
  unsigned u = __float_as_uint(f);
  return (u + 0x7fffu + ((u >> 16) & 1u)) >> 16;
}
__device__ inline unsigned pack2(float lo, float hi) {
  return bfr(lo) | (bfr(hi) << 16);
}
__device__ inline float unpk_lo(unsigned v) { return __uint_as_float(v << 16); }
__device__ inline float unpk_hi(unsigned v) { return __uint_as_float(v & 0xffff0000u); }

// ---------------- hist: dual LDS histograms; phT layout [block][bucket] (coalesced rows)
// role B (64 blocks): W1 fp32 -> bf16 transposed Wtg.  NO global atomics.
__global__ __launch_bounds__(256) void k_hist(const int* __restrict__ dst,
                                              const int* __restrict__ src,
                                              int* __restrict__ phT,
                                              const float* __restrict__ W,
                                              unsigned short* __restrict__ Wtg,
                                              int E, int NBKT, int ECH, int K2) {
  __shared__ int hist[6400];
  int b = blockIdx.x, t = threadIdx.x;
  if (b >= PB) {
    int i = (b - PB) * 256 + t;
    if (i < 128 * 128) {
      int k = i >> 7, n = i & 127;
      Wtg[n * 128 + k] = (unsigned short)bfr(W[k * 128 + n]);
    }
    return;
  }
  int* histD = hist;
  int* histS = hist + NBKT;
  for (int k = t; k < K2; k += 256) hist[k] = 0;
  __syncthreads();
  int st = b * ECH, en = min(E, st + ECH);
  for (int i = st + t; i < en; i += 256) {
    atomicAdd(&histD[dst[i] >> SHIFT], 1);
    atomicAdd(&histS[src[i] >> SHIFT], 1);
  }
  __syncthreads();
  for (int k = t; k < K2; k += 256) phT[(size_t)b * K2 + k] = hist[k];
}

// ---------------- tots: per-bucket totals over blocks (coalesced column sums)
__global__ __launch_bounds__(256) void k_tots(const int* __restrict__ phT,
                                              int* __restrict__ tot, int K2) {
  int k = blockIdx.x * 256 + threadIdx.x;
  if (k < K2) {
    int s = 0;
    for (int b = 0; b < PB; ++b) s += phT[(size_t)b * K2 + k];
    tot[k] = s;
  }
}

// ---------------- scan3: redundant in-LDS exclusive scan of tot (K2 entries),
// then per-bucket column rewrite of phT to running prefixes
__global__ __launch_bounds__(256) void k_scan3(int* __restrict__ phT,
                                               const int* __restrict__ tot, int K2) {
  __shared__ int ltot[6400];
  __shared__ int sc[256];
  int t = threadIdx.x;
  for (int i = t; i < K2; i += 256) ltot[i] = tot[i];
  __syncthreads();
  int C = (K2 + 255) / 256;
  int c0 = t * C;
  int s = 0;
  for (int j = 0; j < C; ++j) {
    int idx = c0 + j;
    if (idx < K2) s += ltot[idx];
  }
  sc[t] = s;
  __syncthreads();
  for (int off = 1; off < 256; off <<= 1) {
    int x = (t >= off) ? sc[t - off] : 0;
    __syncthreads();
    sc[t] += x;
    __syncthreads();
  }
  int run = sc[t] - s;  // exclusive base for this thread's chunk
  for (int j = 0; j < C; ++j) {
    int idx = c0 + j;
    if (idx < K2) {
      int v = ltot[idx];
      ltot[idx] = run;
      run += v;
    }
  }
  __syncthreads();

  int k = blockIdx.x * 256 + t;
  if (k < K2) {
    int r = ltot[k];
    for (int b = 0; b < PB; ++b) {
      size_t idx = (size_t)b * K2 + k;
      int v = phT[idx];
      phT[idx] = r;
      r += v;
    }
  }
}

// ---------------- FUSED: dual pscat (role A, PB blocks, XCD-remapped) || MFMA gemm
// gemm writes UNSCALED h = x@W1 in fp8 e4m3 (no dinv dependency -> full fusion)
__global__ __launch_bounds__(256) void k_scat_gemm(
    const int* __restrict__ src, const int* __restrict__ dst,
    const int* __restrict__ phT, int* __restrict__ eb,
    const float* __restrict__ x, const unsigned short* __restrict__ Wtg,
    unsigned short* __restrict__ hu8, int M, int E, int NBKT, int ECH, int K2) {
  __shared__ int shm[6400];  // 25.6 KB: cursors or gemm x-tile
  int p = blockIdx.x, t = threadIdx.x;

  if (p < PB) {
    // XCD-aware remap: consecutive logical chunks (which share eb cachelines)
    // land on the same XCD (blockIdx % 8 == XCD, round-robin dispatch).
    int b = ((p & 7) << 5) | (p >> 3);
    int* curD = shm;
    int* curS = shm + NBKT;
    for (int k = t; k < K2; k += 256) shm[k] = phT[(size_t)b * K2 + k];
    __syncthreads();
    int st = b * ECH, en = min(E, st + ECH);
    for (int i = st + t * 4; i < en; i += 1024) {
      if (i + 3 < en) {
        int4 s4 = *(const int4*)(src + i);
        int4 d4 = *(const int4*)(dst + i);
        int p0 = atomicAdd(&curD[d4.x >> SHIFT], 1);
        int p1 = atomicAdd(&curD[d4.y >> SHIFT], 1);
        int p2 = atomicAdd(&curD[d4.z >> SHIFT], 1);
        int p3 = atomicAdd(&curD[d4.w >> SHIFT], 1);
        eb[p0] = s4.x | ((d4.x & (RPB - 1)) << 26);
        eb[p1] = s4.y | ((d4.y & (RPB - 1)) << 26);
        eb[p2] = s4.z | ((d4.z & (RPB - 1)) << 26);
        eb[p3] = s4.w | ((d4.w & (RPB - 1)) << 26);
        int q0 = atomicAdd(&curS[s4.x >> SHIFT], 1);
        int q1 = atomicAdd(&curS[s4.y >> SHIFT], 1);
        int q2 = atomicAdd(&curS[s4.z >> SHIFT], 1);
        int q3 = atomicAdd(&curS[s4.w >> SHIFT], 1);
        eb[q0] = d4.x | ((s4.x & (RPB - 1)) << 26);
        eb[q1] = d4.y | ((s4.y & (RPB - 1)) << 26);
        eb[q2] = d4.z | ((s4.z & (RPB - 1)) << 26);
        eb[q3] = d4.w | ((s4.w & (RPB - 1)) << 26);
      } else {
        for (int j = i; j < en; ++j) {
          int d = dst[j], s = src[j];
          int pos = atomicAdd(&curD[d >> SHIFT], 1);
          eb[pos] = s | ((d & (RPB - 1)) << 26);
          int qos = atomicAdd(&curS[s >> SHIFT], 1);
          eb[qos] = d | ((s & (RPB - 1)) << 26);
        }
      }
    }
    return;
  }

  // ---- MFMA gemm role: h = x@W1 (unscaled), fp8 e4m3 packed
  int row0 = (p - PB) * 64;
  if (row0 >= M) return;
  unsigned short* xs = (unsigned short*)shm;  // [64][136]

  for (int i = t; i < 2048; i += 256) {
    int r = i >> 5;
    int rg = row0 + r;
    int rc = rg < M ? rg : M - 1;
    float4 v = ((const float4*)x)[(size_t)rc * 32 + (i & 31)];
    *(uint2*)&xs[r * 136 + (i & 31) * 4] = make_uint2(pack2(v.x, v.y), pack2(v.z, v.w));
  }
  __syncthreads();

  int lane = t & 63;
  int wid = t >> 6;
  int l15 = lane & 15;
  int quad = lane >> 4;
  int mloc = wid * 16 + l15;

  f32x4 acc[8];
  #pragma unroll
  for (int ct = 0; ct < 8; ++ct) acc[ct] = (f32x4){0.f, 0.f, 0.f, 0.f};

  #pragma unroll
  for (int k0 = 0; k0 < 128; k0 += 32) {
    short8 af = *(const short8*)&xs[mloc * 136 + k0 + quad * 8];
    #pragma unroll
    for (int ct = 0; ct < 8; ++ct) {
      short8 bf = *(const short8*)(Wtg + (ct * 16 + l15) * 128 + k0 + quad * 8);
      acc[ct] = __builtin_amdgcn_mfma_f32_16x16x32_bf16(af, bf, acc[ct], 0, 0, 0);
    }
  }

  int rowbase = row0 + wid * 16 + quad * 4;
  #pragma unroll
  for (int ct = 0; ct < 8; ++ct) {
    #pragma unroll
    for (int r = 0; r < 4; ++r) {
      float v = acc[ct][r];
      float vp = __shfl_xor(v, 1, 64);
      int row = rowbase + r;
      if (!(lane & 1) && row < M) {
        int pk = __builtin_amdgcn_cvt_pk_fp8_f32(v, vp, 0, false);
        hu8[(size_t)row * 64 + ct * 8 + (l15 >> 1)] = (unsigned short)(pk & 0xffff);
      }
    }
  }
}

// ---------------- rowdeg: per-dst-bucket LDS count of local rows -> dinv
__global__ __launch_bounds__(256) void k_rowdeg(const int* __restrict__ eb,
                                                const int* __restrict__ phT,
                                                float* __restrict__ dinv,
                                                int N, int NBKT) {
  __shared__ int cnt[RPB];
  int bkt = blockIdx.x, t = threadIdx.x;
  if (t < RPB) cnt[t] = 0;
  __syncthreads();
  int lo = phT[bkt];
  int hi = phT[bkt + 1];
  for (int i = lo + t; i < hi; i += 256)
    atomicAdd(&cnt[(unsigned)eb[i] >> 26], 1);
  __syncthreads();
  if (t < RPB) {
    int r = bkt * RPB + t;
    if (r < N) dinv[r] = rsqrtf((float)cnt[t] + 1.0f);
  }
}

// ---------------- bucketed aggregate + fused ssum prologue + fused weighted reduce
// prologue: ssl[rl] = sum dinv[dst] over out-edges of this bucket's rows
// sort:     srt[pos]=src, sdi[pos]=dinv[src]  (one L2 gather per edge, high MLP)
// agg:      padded 8-wide batches; coefficient = LDS broadcast (mask folds in)
// epilogue: a1 = relu(di*(acc + di*h_self) + b1); vpart += w*a1, w=di*(ssl+di)
__global__ __launch_bounds__(256) void k_bagg(
    const unsigned short* __restrict__ hu8, const int* __restrict__ eb,
    const int* __restrict__ phT, const float* __restrict__ dinv,
    const float* __restrict__ b1, float* __restrict__ vpart,
    int N, int E, int NBKT, int K2) {
  __shared__ int raw[CAP];
  __shared__ int srt[CAP];
  __shared__ float sdi[CAP];
  __shared__ int rh[RPB + 1];
  __shared__ int rcur[RPB];
  __shared__ float ssl[RPB];
  int bkt = blockIdx.x, t = threadIdx.x;
  int lane = t & 63, wid = t >> 6;

  // ---- ssum prologue (src-table range of this bucket)
  if (t < RPB) ssl[t] = 0.f;
  __syncthreads();
  {
    int slo = phT[NBKT + bkt];
    int shi = (NBKT + bkt + 1 < K2) ? phT[NBKT + bkt + 1] : 2 * E;
    for (int i = slo + t; i < shi; i += 256) {
      int v = eb[i];
      atomicAdd(&ssl[(unsigned)v >> 26], dinv[v & 0x3FFFFFF]);
    }
  }

  int lo = phT[bkt];
  int hi = phT[bkt + 1];

  float ax[8], ay[8];
  #pragma unroll
  for (int k = 0; k < 8; ++k) { ax[k] = 0.f; ay[k] = 0.f; }

  for (int clo = lo; clo < hi; clo += CAP) {
    int cnt = min(CAP, hi - clo);
    __syncthreads();
    if (t <= RPB) rh[t] = 0;
    __syncthreads();
    for (int i = t; i < cnt; i += 256) {
      int v = eb[clo + i];
      raw[i] = v;
      atomicAdd(&rh[((unsigned)v >> 26) + 1], 1);
    }
    __syncthreads();
    if (t < 32) {
      int x = rh[t + 1];
      #pragma unroll
      for (int o = 1; o < 32; o <<= 1) {
        int y = __shfl_up(x, o, 64);
        if (t >= o) x += y;
      }
      rh[t + 1] = x;
    }
    __syncthreads();
    if (t < RPB) rcur[t] = rh[t];
    __syncthreads();
    for (int i = t; i < cnt; i += 256) {
      int v = raw[i];
      int r = (unsigned)v >> 26;
      int pos = atomicAdd(&rcur[r], 1);
      int s = v & 0x3FFFFFF;
      srt[pos] = s;
      sdi[pos] = dinv[s];
    }
    __syncthreads();

    #pragma unroll
    for (int k = 0; k < 8; ++k) {
      int rl = wid + k * 4;
      int beg = rh[rl], end = rh[rl + 1];
      for (int j = beg; j < end; j += 8) {
        #pragma unroll
        for (int d = 0; d < 8; ++d) {
          int jd = j + d;
          int idx = jd < end ? jd : end - 1;
          int s = srt[idx];
          float e = jd < end ? sdi[idx] : 0.f;
          unsigned v = hu8[(s << 6) + lane];
          f32x2 f = __builtin_amdgcn_cvt_pk_f32_fp8((int)v, false);
          ax[k] = fmaf(e, f.x, ax[k]);
          ay[k] = fmaf(e, f.y, ay[k]);
        }
      }
    }
  }
  __syncthreads();

  // epilogue: a1 = relu(di*(acc + di*h_self) + b1); accumulate w*a1
  float2 bb = *(const float2*)(b1 + lane * 2);
  float vx = 0.f, vy = 0.f;
  #pragma unroll
  for (int k = 0; k < 8; ++k) {
    int rl = wid + k * 4;
    int r = bkt * RPB + rl;
    if (r < N) {
      float di = dinv[r];
      unsigned gr = hu8[(r << 6) + lane];
      f32x2 fg = __builtin_amdgcn_cvt_pk_f32_fp8((int)gr, false);
      float hx = fmaxf(fmaf(di, fmaf(di, fg.x, ax[k]), bb.x), 0.f);
      float hy = fmaxf(fmaf(di, fmaf(di, fg.y, ay[k]), bb.y), 0.f);
      float w = di * (ssl[rl] + di);
      vx = fmaf(w, hx, vx);
      vy = fmaf(w, hy, vy);
    }
  }
  float2* red = (float2*)raw;  // reuse LDS (all srt/raw reads done)
  red[t] = make_float2(vx, vy);
  __syncthreads();
  if (t < 64) {
    float2 a = red[t], b = red[t + 64], c = red[t + 128], d2 = red[t + 192];
    vpart[(size_t)bkt * D + t * 2]     = (a.x + b.x) + (c.x + d2.x);
    vpart[(size_t)bkt * D + t * 2 + 1] = (a.y + b.y) + (c.y + d2.y);
  }
}

// ---------------- vred2: reduce NBKT per-bucket partials -> 64 partials
__global__ __launch_bounds__(128) void k_vred2(const float* __restrict__ vpart,
                                               float* __restrict__ vpart2, int NBKT) {
  int t = threadIdx.x;
  float s = 0.f;
  for (int i = blockIdx.x; i < NBKT; i += 64) s += vpart[(size_t)i * D + t];
  vpart2[(size_t)blockIdx.x * D + t] = s;
}

// ---------------- final: v = sum partials; out = (1/N)*v@W2 + b2
__global__ __launch_bounds__(1024) void k_final(const float* __restrict__ vpart,
                                                int npart,
                                                const float* __restrict__ W2,
                                                const float* __restrict__ b2,
                                                float* __restrict__ out, float invN) {
  __shared__ float seg[8][128];
  __shared__ float vs[128];
  int t = threadIdx.x;
  int c = t & 127, sg = t >> 7;
  float s = 0.f;
  for (int b = sg; b < npart; b += 8) s += vpart[(size_t)b * D + c];
  seg[sg][c] = s;
  __syncthreads();
  if (t < 128) {
    float tot = 0.f;
    #pragma unroll
    for (int k = 0; k < 8; ++k) tot += seg[k][c];
    vs[c] = tot;
  }
  __syncthreads();
  if (t < 128) {
    float o = 0.f;
    for (int k = 0; k < 128; ++k) o = fmaf(vs[k], W2[k * D + c], o);
    out[c] = fmaf(o, invN, b2[c]);
  }
}

extern "C" void kernel_launch(void* const* d_in, const int* in_sizes, int n_in,
                              void* d_out, int out_size, void* d_ws, size_t ws_size,
                              hipStream_t stream) {
  const float* x  = (const float*)d_in[0];
  const int*   ei = (const int*)d_in[1];
  const float* W1 = (const float*)d_in[2];
  const float* b1 = (const float*)d_in[3];
  const float* W2 = (const float*)d_in[4];
  const float* b2 = (const float*)d_in[5];
  float* out = (float*)d_out;

  int N = in_sizes[0] / D;
  int E = in_sizes[1] / 2;
  const int* src = ei;
  const int* dst = ei + E;

  const int NBKT = (N + RPB - 1) / RPB;                    // 3125
  const int K2   = 2 * NBKT;                               // 6250 (both tables)
  const int ECH  = (((E + PB - 1) / PB) + 3) & ~3;         // 6252 (x4 aligned)
  const int TB   = (K2 + 255) / 256;                       // 25
  const int NGEMM = (N + 63) / 64;                         // 1563

  char* p = (char*)d_ws;
  float* dinv  = (float*)p;      p += (size_t)N * 4;
  int*   tot   = (int*)p;        p += 8192 * 4;
  int*   phT   = (int*)p;        p += (size_t)PB * K2 * 4;
  int*   eb    = (int*)p;        p += (size_t)(2 * E) * 4;
  p = (char*)(((uintptr_t)p + 255) & ~(uintptr_t)255);
  unsigned short* Wtg = (unsigned short*)p;  p += 128 * 128 * 2;
  p = (char*)(((uintptr_t)p + 255) & ~(uintptr_t)255);
  unsigned short* hu8 = (unsigned short*)p;  p += (size_t)N * 64 * 2;
  p = (char*)(((uintptr_t)p + 255) & ~(uintptr_t)255);
  float* vpart  = (float*)p;     p += (size_t)NBKT * D * 4;
  float* vpart2 = (float*)p;

  k_hist<<<PB + 64, 256, 0, stream>>>(dst, src, phT, W1, Wtg, E, NBKT, ECH, K2);

  k_tots<<<TB, 256, 0, stream>>>(phT, tot, K2);

  k_scan3<<<TB, 256, 0, stream>>>(phT, tot, K2);

  k_scat_gemm<<<PB + NGEMM, 256, 0, stream>>>(src, dst, phT, eb, x, Wtg, hu8,
                                              N, E, NBKT, ECH, K2);

  k_rowdeg<<<NBKT, 256, 0, stream>>>(eb, phT, dinv, N, NBKT);

  k_bagg<<<NBKT, 256, 0, stream>>>(hu8, eb, phT, dinv, b1, vpart, N, E, NBKT, K2);

  k_vred2<<<64, 128, 0, stream>>>(vpart, vpart2, NBKT);

  k_final<<<1, 1024, 0, stream>>>(vpart2, 64, W2, b2, out, 1.0f / N);
}

// Round 3
// 252.623 us; speedup vs baseline: 1.3010x; 1.1216x over previous
//
#include <hip/hip_runtime.h>

#define D 128
#define RPB 32          // rows per bucket
#define SHIFT 5         // log2(RPB)
#define PB 256          // partition blocks
#define CAP 1536        // max edges per bucket chunk (avg 512)
#define CAPP (CAP + RPB * 7)  // padded capacity (each row rounds up to x8)

typedef __attribute__((ext_vector_type(8))) short short8;
typedef __attribute__((ext_vector_type(4))) float f32x4;
typedef __attribute__((ext_vector_type(2))) float f32x2;

// ---- bf16 pack helpers (round-to-nearest-even)
__device__ inline unsigned bfr(float f) {
  unsigned u = __float_as_uint(f);
  return (u + 0x7fffu + ((u >> 16) & 1u)) >> 16;
}
__device__ inline unsigned pack2(float lo, float hi) {
  return bfr(lo) | (bfr(hi) << 16);
}

// ---------------- hist: dual LDS histograms; 1024 threads + int4 loads for MLP
// (round-1 counters: 256-thread version was latency-bound: occ 9.5%, VALU 0.9%)
// role B (16 blocks): W1 fp32 -> bf16 transposed Wtg.
__global__ __launch_bounds__(1024) void k_hist(const int* __restrict__ dst,
                                               const int* __restrict__ src,
                                               int* __restrict__ phT,
                                               const float* __restrict__ W,
                                               unsigned short* __restrict__ Wtg,
                                               int E, int NBKT, int ECH, int K2) {
  __shared__ int hist[6400];
  int b = blockIdx.x, t = threadIdx.x;
  if (b >= PB) {
    int i = (b - PB) * 1024 + t;
    if (i < 128 * 128) {
      int k = i >> 7, n = i & 127;
      Wtg[n * 128 + k] = (unsigned short)bfr(W[k * 128 + n]);
    }
    return;
  }
  int* histD = hist;
  int* histS = hist + NBKT;
  for (int k = t; k < K2; k += 1024) hist[k] = 0;
  __syncthreads();
  int st = b * ECH, en = min(E, st + ECH);
  for (int i = st + t * 4; i < en; i += 4096) {
    if (i + 3 < en) {
      int4 d4 = *(const int4*)(dst + i);
      int4 s4 = *(const int4*)(src + i);
      atomicAdd(&histD[d4.x >> SHIFT], 1);
      atomicAdd(&histD[d4.y >> SHIFT], 1);
      atomicAdd(&histD[d4.z >> SHIFT], 1);
      atomicAdd(&histD[d4.w >> SHIFT], 1);
      atomicAdd(&histS[s4.x >> SHIFT], 1);
      atomicAdd(&histS[s4.y >> SHIFT], 1);
      atomicAdd(&histS[s4.z >> SHIFT], 1);
      atomicAdd(&histS[s4.w >> SHIFT], 1);
    } else {
      for (int j = i; j < en; ++j) {
        atomicAdd(&histD[dst[j] >> SHIFT], 1);
        atomicAdd(&histS[src[j] >> SHIFT], 1);
      }
    }
  }
  __syncthreads();
  for (int k = t; k < K2; k += 1024) phT[(size_t)b * K2 + k] = hist[k];
}

// ---------------- tots: per-bucket totals over blocks (coalesced column sums)
__global__ __launch_bounds__(256) void k_tots(const int* __restrict__ phT,
                                              int* __restrict__ tot, int K2) {
  int k = blockIdx.x * 256 + threadIdx.x;
  if (k < K2) {
    int s = 0;
    for (int b = 0; b < PB; ++b) s += phT[(size_t)b * K2 + k];
    tot[k] = s;
  }
}

// ---------------- scan3: redundant in-LDS exclusive scan of tot (K2 entries),
// then per-bucket column rewrite of phT to running prefixes
__global__ __launch_bounds__(256) void k_scan3(int* __restrict__ phT,
                                               const int* __restrict__ tot, int K2) {
  __shared__ int ltot[6400];
  __shared__ int sc[256];
  int t = threadIdx.x;
  for (int i = t; i < K2; i += 256) ltot[i] = tot[i];
  __syncthreads();
  int C = (K2 + 255) / 256;
  int c0 = t * C;
  int s = 0;
  for (int j = 0; j < C; ++j) {
    int idx = c0 + j;
    if (idx < K2) s += ltot[idx];
  }
  sc[t] = s;
  __syncthreads();
  for (int off = 1; off < 256; off <<= 1) {
    int x = (t >= off) ? sc[t - off] : 0;
    __syncthreads();
    sc[t] += x;
    __syncthreads();
  }
  int run = sc[t] - s;  // exclusive base for this thread's chunk
  for (int j = 0; j < C; ++j) {
    int idx = c0 + j;
    if (idx < K2) {
      int v = ltot[idx];
      ltot[idx] = run;
      run += v;
    }
  }
  __syncthreads();

  int k = blockIdx.x * 256 + t;
  if (k < K2) {
    int r = ltot[k];
    for (int b = 0; b < PB; ++b) {
      size_t idx = (size_t)b * K2 + k;
      int v = phT[idx];
      phT[idx] = r;
      r += v;
    }
  }
}

// ---------------- FUSED: dual pscat (role A, PB blocks, XCD-remapped) || MFMA gemm
// gemm writes UNSCALED h = x@W1 in fp8 e4m3 (no dinv dependency -> full fusion)
__global__ __launch_bounds__(256) void k_scat_gemm(
    const int* __restrict__ src, const int* __restrict__ dst,
    const int* __restrict__ phT, int* __restrict__ eb,
    const float* __restrict__ x, const unsigned short* __restrict__ Wtg,
    unsigned short* __restrict__ hu8, int M, int E, int NBKT, int ECH, int K2) {
  __shared__ int shm[6400];  // 25.6 KB: cursors or gemm x-tile
  int p = blockIdx.x, t = threadIdx.x;

  if (p < PB) {
    // XCD-aware remap: consecutive logical chunks (which share eb cachelines)
    // land on the same XCD (blockIdx % 8 == XCD, round-robin dispatch).
    int b = ((p & 7) << 5) | (p >> 3);
    int* curD = shm;
    int* curS = shm + NBKT;
    for (int k = t; k < K2; k += 256) shm[k] = phT[(size_t)b * K2 + k];
    __syncthreads();
    int st = b * ECH, en = min(E, st + ECH);
    for (int i = st + t * 4; i < en; i += 1024) {
      if (i + 3 < en) {
        int4 s4 = *(const int4*)(src + i);
        int4 d4 = *(const int4*)(dst + i);
        int p0 = atomicAdd(&curD[d4.x >> SHIFT], 1);
        int p1 = atomicAdd(&curD[d4.y >> SHIFT], 1);
        int p2 = atomicAdd(&curD[d4.z >> SHIFT], 1);
        int p3 = atomicAdd(&curD[d4.w >> SHIFT], 1);
        eb[p0] = s4.x | ((d4.x & (RPB - 1)) << 26);
        eb[p1] = s4.y | ((d4.y & (RPB - 1)) << 26);
        eb[p2] = s4.z | ((d4.z & (RPB - 1)) << 26);
        eb[p3] = s4.w | ((d4.w & (RPB - 1)) << 26);
        int q0 = atomicAdd(&curS[s4.x >> SHIFT], 1);
        int q1 = atomicAdd(&curS[s4.y >> SHIFT], 1);
        int q2 = atomicAdd(&curS[s4.z >> SHIFT], 1);
        int q3 = atomicAdd(&curS[s4.w >> SHIFT], 1);
        eb[q0] = d4.x | ((s4.x & (RPB - 1)) << 26);
        eb[q1] = d4.y | ((s4.y & (RPB - 1)) << 26);
        eb[q2] = d4.z | ((s4.z & (RPB - 1)) << 26);
        eb[q3] = d4.w | ((s4.w & (RPB - 1)) << 26);
      } else {
        for (int j = i; j < en; ++j) {
          int d = dst[j], s = src[j];
          int pos = atomicAdd(&curD[d >> SHIFT], 1);
          eb[pos] = s | ((d & (RPB - 1)) << 26);
          int qos = atomicAdd(&curS[s >> SHIFT], 1);
          eb[qos] = d | ((s & (RPB - 1)) << 26);
        }
      }
    }
    return;
  }

  // ---- MFMA gemm role: h = x@W1 (unscaled), fp8 e4m3 packed
  int row0 = (p - PB) * 64;
  if (row0 >= M) return;
  unsigned short* xs = (unsigned short*)shm;  // [64][136]

  for (int i = t; i < 2048; i += 256) {
    int r = i >> 5;
    int rg = row0 + r;
    int rc = rg < M ? rg : M - 1;
    float4 v = ((const float4*)x)[(size_t)rc * 32 + (i & 31)];
    *(uint2*)&xs[r * 136 + (i & 31) * 4] = make_uint2(pack2(v.x, v.y), pack2(v.z, v.w));
  }
  __syncthreads();

  int lane = t & 63;
  int wid = t >> 6;
  int l15 = lane & 15;
  int quad = lane >> 4;
  int mloc = wid * 16 + l15;

  f32x4 acc[8];
  #pragma unroll
  for (int ct = 0; ct < 8; ++ct) acc[ct] = (f32x4){0.f, 0.f, 0.f, 0.f};

  #pragma unroll
  for (int k0 = 0; k0 < 128; k0 += 32) {
    short8 af = *(const short8*)&xs[mloc * 136 + k0 + quad * 8];
    #pragma unroll
    for (int ct = 0; ct < 8; ++ct) {
      short8 bf = *(const short8*)(Wtg + (ct * 16 + l15) * 128 + k0 + quad * 8);
      acc[ct] = __builtin_amdgcn_mfma_f32_16x16x32_bf16(af, bf, acc[ct], 0, 0, 0);
    }
  }

  int rowbase = row0 + wid * 16 + quad * 4;
  #pragma unroll
  for (int ct = 0; ct < 8; ++ct) {
    #pragma unroll
    for (int r = 0; r < 4; ++r) {
      float v = acc[ct][r];
      float vp = __shfl_xor(v, 1, 64);
      int row = rowbase + r;
      if (!(lane & 1) && row < M) {
        int pk = __builtin_amdgcn_cvt_pk_fp8_f32(v, vp, 0, false);
        hu8[(size_t)row * 64 + ct * 8 + (l15 >> 1)] = (unsigned short)(pk & 0xffff);
      }
    }
  }
}

// ---------------- rowdeg: per-dst-bucket LDS count of local rows -> dinv
__global__ __launch_bounds__(256) void k_rowdeg(const int* __restrict__ eb,
                                                const int* __restrict__ phT,
                                                float* __restrict__ dinv,
                                                int N, int NBKT) {
  __shared__ int cnt[RPB];
  int bkt = blockIdx.x, t = threadIdx.x;
  if (t < RPB) cnt[t] = 0;
  __syncthreads();
  int lo = phT[bkt];
  int hi = phT[bkt + 1];
  for (int i = lo + t; i < hi; i += 256)
    atomicAdd(&cnt[(unsigned)eb[i] >> 26], 1);
  __syncthreads();
  if (t < RPB) {
    int r = bkt * RPB + t;
    if (r < N) dinv[r] = rsqrtf((float)cnt[t] + 1.0f);
  }
}

// ---------------- bucketed aggregate + fused ssum prologue + fused weighted reduce
// Sort phase now pre-pads every row's list to x8 (pad weight 0) and fuses
// {hu8 byte-offset, dinv[src]} into one int2 per edge (single ds_read_b64,
// imm-offset batched). Hot loop per edge: ds_read_b64 + v_add + load_d16 +
// cvt + 2 fma, no selects, no bounds checks.
__global__ __launch_bounds__(256) void k_bagg(
    const unsigned short* __restrict__ hu8, const int* __restrict__ eb,
    const int* __restrict__ phT, const float* __restrict__ dinv,
    const float* __restrict__ b1, float* __restrict__ vpart,
    int N, int E, int NBKT, int K2) {
  __shared__ int raw[CAP];
  __shared__ int2 srtdi[CAPP];
  __shared__ int rcnt[RPB];
  __shared__ int rhp[RPB + 1];
  __shared__ int rcur[RPB];
  __shared__ float ssl[RPB];
  int bkt = blockIdx.x, t = threadIdx.x;
  int lane = t & 63, wid = t >> 6;
  int lane2 = lane << 1;
  const char* hub = (const char*)hu8;

  // ---- ssum prologue (src-table range of this bucket)
  if (t < RPB) ssl[t] = 0.f;
  __syncthreads();
  {
    int slo = phT[NBKT + bkt];
    int shi = (NBKT + bkt + 1 < K2) ? phT[NBKT + bkt + 1] : 2 * E;
    for (int i = slo + t; i < shi; i += 256) {
      int v = eb[i];
      atomicAdd(&ssl[(unsigned)v >> 26], dinv[v & 0x3FFFFFF]);
    }
  }

  int lo = phT[bkt];
  int hi = phT[bkt + 1];

  f32x2 acc[8];
  #pragma unroll
  for (int k = 0; k < 8; ++k) acc[k] = (f32x2){0.f, 0.f};

  for (int clo = lo; clo < hi; clo += CAP) {
    int cnt = min(CAP, hi - clo);
    __syncthreads();  // all waves done with srtdi/ssl of previous phase
    if (t < RPB) rcnt[t] = 0;
    __syncthreads();
    for (int i = t; i < cnt; i += 256) {
      int v = eb[clo + i];
      raw[i] = v;
      atomicAdd(&rcnt[(unsigned)v >> 26], 1);
    }
    __syncthreads();
    if (t < RPB) {
      int x = (rcnt[t] + 7) & ~7;  // padded count
      int orig = x;
      #pragma unroll
      for (int o = 1; o < RPB; o <<= 1) {
        int y = __shfl_up(x, o, 64);
        if (t >= o) x += y;
      }
      rhp[t + 1] = x;
      if (t == 0) rhp[0] = 0;
      rcur[t] = x - orig;  // padded start
    }
    __syncthreads();
    for (int i = t; i < cnt; i += 256) {
      int v = raw[i];
      int r = (unsigned)v >> 26;
      int pos = atomicAdd(&rcur[r], 1);
      int s = v & 0x3FFFFFF;
      srtdi[pos] = make_int2(s << 7, __float_as_int(dinv[s]));
    }
    __syncthreads();
    if (t < RPB) {  // fill pad region with weight-0 entries
      for (int i = rcur[t]; i < rhp[t + 1]; ++i) srtdi[i] = make_int2(0, 0);
    }
    __syncthreads();

    #pragma unroll
    for (int k = 0; k < 8; ++k) {
      int rl = wid + k * 4;
      int beg = rhp[rl], end = rhp[rl + 1];
      for (int j = beg; j < end; j += 8) {
        #pragma unroll
        for (int d = 0; d < 8; ++d) {
          int2 e = srtdi[j + d];
          unsigned v = *(const unsigned short*)(hub + (unsigned)e.x + lane2);
          f32x2 f = __builtin_amdgcn_cvt_pk_f32_fp8((int)v, false);
          float w = __int_as_float(e.y);
          acc[k].x = fmaf(w, f.x, acc[k].x);
          acc[k].y = fmaf(w, f.y, acc[k].y);
        }
      }
    }
  }
  __syncthreads();

  // epilogue: a1 = relu(di*(acc + di*h_self) + b1); accumulate w*a1
  float2 bb = *(const float2*)(b1 + lane2);
  float vx = 0.f, vy = 0.f;
  #pragma unroll
  for (int k = 0; k < 8; ++k) {
    int rl = wid + k * 4;
    int r = bkt * RPB + rl;
    if (r < N) {
      float di = dinv[r];
      unsigned gr = *(const unsigned short*)(hub + ((unsigned)r << 7) + lane2);
      f32x2 fg = __builtin_amdgcn_cvt_pk_f32_fp8((int)gr, false);
      float hx = fmaxf(fmaf(di, fmaf(di, fg.x, acc[k].x), bb.x), 0.f);
      float hy = fmaxf(fmaf(di, fmaf(di, fg.y, acc[k].y), bb.y), 0.f);
      float w = di * (ssl[rl] + di);
      vx = fmaf(w, hx, vx);
      vy = fmaf(w, hy, vy);
    }
  }
  float2* red = (float2*)raw;  // reuse LDS (all srtdi/raw reads done)
  red[t] = make_float2(vx, vy);
  __syncthreads();
  if (t < 64) {
    float2 a = red[t], b = red[t + 64], c = red[t + 128], d2 = red[t + 192];
    vpart[(size_t)bkt * D + t * 2]     = (a.x + b.x) + (c.x + d2.x);
    vpart[(size_t)bkt * D + t * 2 + 1] = (a.y + b.y) + (c.y + d2.y);
  }
}

// ---------------- vred2: reduce NBKT per-bucket partials -> 64 partials
__global__ __launch_bounds__(128) void k_vred2(const float* __restrict__ vpart,
                                               float* __restrict__ vpart2, int NBKT) {
  int t = threadIdx.x;
  float s = 0.f;
  for (int i = blockIdx.x; i < NBKT; i += 64) s += vpart[(size_t)i * D + t];
  vpart2[(size_t)blockIdx.x * D + t] = s;
}

// ---------------- final: v = sum partials; out = (1/N)*v@W2 + b2
__global__ __launch_bounds__(1024) void k_final(const float* __restrict__ vpart,
                                                int npart,
                                                const float* __restrict__ W2,
                                                const float* __restrict__ b2,
                                                float* __restrict__ out, float invN) {
  __shared__ float seg[8][128];
  __shared__ float vs[128];
  int t = threadIdx.x;
  int c = t & 127, sg = t >> 7;
  float s = 0.f;
  for (int b = sg; b < npart; b += 8) s += vpart[(size_t)b * D + c];
  seg[sg][c] = s;
  __syncthreads();
  if (t < 128) {
    float tot = 0.f;
    #pragma unroll
    for (int k = 0; k < 8; ++k) tot += seg[k][c];
    vs[c] = tot;
  }
  __syncthreads();
  if (t < 128) {
    float o = 0.f;
    for (int k = 0; k < 128; ++k) o = fmaf(vs[k], W2[k * D + c], o);
    out[c] = fmaf(o, invN, b2[c]);
  }
}

extern "C" void kernel_launch(void* const* d_in, const int* in_sizes, int n_in,
                              void* d_out, int out_size, void* d_ws, size_t ws_size,
                              hipStream_t stream) {
  const float* x  = (const float*)d_in[0];
  const int*   ei = (const int*)d_in[1];
  const float* W1 = (const float*)d_in[2];
  const float* b1 = (const float*)d_in[3];
  const float* W2 = (const float*)d_in[4];
  const float* b2 = (const float*)d_in[5];
  float* out = (float*)d_out;

  int N = in_sizes[0] / D;
  int E = in_sizes[1] / 2;
  const int* src = ei;
  const int* dst = ei + E;

  const int NBKT = (N + RPB - 1) / RPB;                    // 3125
  const int K2   = 2 * NBKT;                               // 6250 (both tables)
  const int ECH  = (((E + PB - 1) / PB) + 3) & ~3;         // 6252 (x4 aligned)
  const int TB   = (K2 + 255) / 256;                       // 25
  const int NGEMM = (N + 63) / 64;                         // 1563

  char* p = (char*)d_ws;
  float* dinv  = (float*)p;      p += (size_t)N * 4;
  int*   tot   = (int*)p;        p += 8192 * 4;
  int*   phT   = (int*)p;        p += (size_t)PB * K2 * 4;
  int*   eb    = (int*)p;        p += (size_t)(2 * E) * 4;
  p = (char*)(((uintptr_t)p + 255) & ~(uintptr_t)255);
  unsigned short* Wtg = (unsigned short*)p;  p += 128 * 128 * 2;
  p = (char*)(((uintptr_t)p + 255) & ~(uintptr_t)255);
  unsigned short* hu8 = (unsigned short*)p;  p += (size_t)N * 64 * 2;
  p = (char*)(((uintptr_t)p + 255) & ~(uintptr_t)255);
  float* vpart  = (float*)p;     p += (size_t)NBKT * D * 4;
  float* vpart2 = (float*)p;

  k_hist<<<PB + 16, 1024, 0, stream>>>(dst, src, phT, W1, Wtg, E, NBKT, ECH, K2);

  k_tots<<<TB, 256, 0, stream>>>(phT, tot, K2);

  k_scan3<<<TB, 256, 0, stream>>>(phT, tot, K2);

  k_scat_gemm<<<PB + NGEMM, 256, 0, stream>>>(src, dst, phT, eb, x, Wtg, hu8,
                                              N, E, NBKT, ECH, K2);

  k_rowdeg<<<NBKT, 256, 0, stream>>>(eb, phT, dinv, N, NBKT);

  k_bagg<<<NBKT, 256, 0, stream>>>(hu8, eb, phT, dinv, b1, vpart, N, E, NBKT, K2);

  k_vred2<<<64, 128, 0, stream>>>(vpart, vpart2, NBKT);

  k_final<<<1, 1024, 0, stream>>>(vpart2, 64, W2, b2, out, 1.0f / N);
}